// Round 4
// baseline (718.721 us; speedup 1.0000x reference)
//
#include <hip/hip_runtime.h>
#include <hip/hip_bf16.h>

// PatchedAttention on MI355X (gfx950).
// B=4, T=8192, D=1024, H=16, Dh=64, PATCH=128 -> M=32768 tokens, 256 patches.
// R4: GEMMs upgraded m97-128^2 -> 256^2/BK=64/8-wave phase-split schedule
//     (counted vmcnt(8), XOR-swizzled LDS, setprio around MFMA clusters).
// Workspace layout (bytes):
//   xb   @ 0         : 67,108,864  (x bf16 [32768][1024]; reused as attn-out)
//   wqkv @ 67108864  :  6,291,456  (Wq|Wk|Wv transposed bf16 [3072][1024])
//   wot  @ 73400320  :  2,097,152  (Wo transposed bf16 [1024][1024])
//   bqkv @ 75497472  :     12,288  (fused bias f32 [3072])
//   qkv  @ 75509760  : 201,326,592 (QKV bf16 [32768][3072])

#define DEV static __device__ __forceinline__

typedef __attribute__((ext_vector_type(8))) short short8;   // 8 x bf16 (4 VGPR)
typedef __attribute__((ext_vector_type(4))) float f32x4;    // MFMA C/D frag

DEV unsigned short f2b(float f) {  // fp32 -> bf16 RNE
  unsigned u = __builtin_bit_cast(unsigned, f);
  u += 0x7fffu + ((u >> 16) & 1u);
  return (unsigned short)(u >> 16);
}

DEV void load_lds16(const void* g, void* l) {  // async global->LDS, 16B/lane
  __builtin_amdgcn_global_load_lds(
      (const __attribute__((address_space(1))) void*)g,
      (__attribute__((address_space(3))) void*)l, 16, 0, 0);
}

#define MFMA_BF16(a, b, c) __builtin_amdgcn_mfma_f32_16x16x32_bf16((a), (b), (c), 0, 0, 0)

// ---------------- pre-pass kernels ----------------

__global__ void cvt_x_k(const float* __restrict__ x, unsigned short* __restrict__ xb, int n4) {
  int i = blockIdx.x * blockDim.x + threadIdx.x;
  int stride = gridDim.x * blockDim.x;
  for (; i < n4; i += stride) {
    float4 v = ((const float4*)x)[i];
    ushort4 o;
    o.x = f2b(v.x); o.y = f2b(v.y); o.z = f2b(v.z); o.w = f2b(v.w);
    ((ushort4*)xb)[i] = o;
  }
}

// 4x W [1024][1024] (k-major) fp32 -> Wt [1024][1024] (n-major, k contiguous) bf16.
__global__ void twk4(const float* __restrict__ W0, const float* __restrict__ W1,
                     const float* __restrict__ W2, const float* __restrict__ W3,
                     unsigned short* __restrict__ Dqkv, unsigned short* __restrict__ Dot) {
  __shared__ unsigned short tile[64][65];
  const int w = blockIdx.x >> 8;
  const int t = blockIdx.x & 255;
  const float* W = (w == 0) ? W0 : (w == 1) ? W1 : (w == 2) ? W2 : W3;
  unsigned short* Wt = (w == 3) ? Dot : Dqkv + (size_t)w * 1024 * 1024;
  int k0 = (t >> 4) << 6;
  int n0 = (t & 15) << 6;
  int tx = threadIdx.x & 63;
  int ty = threadIdx.x >> 6;
#pragma unroll
  for (int i = 0; i < 16; ++i) {
    int r = (i << 2) + ty;
    tile[r][tx] = f2b(W[(size_t)(k0 + r) * 1024 + n0 + tx]);
  }
  __syncthreads();
#pragma unroll
  for (int i = 0; i < 16; ++i) {
    int n = (i << 2) + ty;
    Wt[(size_t)(n0 + n) * 1024 + k0 + tx] = tile[tx][n];
  }
}

__global__ void fuse_bias_k(const float* __restrict__ bq, const float* __restrict__ bk,
                            const float* __restrict__ bv, float* __restrict__ bqkv) {
  int i = blockIdx.x * 256 + threadIdx.x;
  if (i < 1024) bqkv[i] = bq[i];
  else if (i < 2048) bqkv[i] = bk[i - 1024];
  else if (i < 3072) bqkv[i] = bv[i - 2048];
}

// ---- GEMM 256x256 tile, BK=64, 8 waves (2M x 4N), phase-split schedule ----
// C[M,N] = A[M,K] * Bt[N,K]^T + bias.
// LDS: 2 K-tile buffers x (A 256x64 | B 256x64) bf16 = 131072 B.
// Swizzle: physical byte-in-row = logical ^ ((row&7)<<4); staged via pre-swizzled
// per-lane GLOBAL source (global_load_lds dest stays linear), read with same XOR
// -> A/B frag reads are 2-way bank aliased only (free).
// Schedule per K-tile t: issue 8 global_load_lds for tile t+1 into other buffer
// (its readers finished a full barrier ago), s_waitcnt vmcnt(8) [counted, never
// 0 in-loop], barrier, then 4 phases: 12 ds_read -> barrier -> lgkmcnt(0) ->
// setprio(1) 16 MFMA setprio(0) -> barrier.

template <bool OUT_F32>
__global__ __launch_bounds__(512, 2)
void gemm256(const unsigned short* __restrict__ A,
             const unsigned short* __restrict__ Bt,
             const float* __restrict__ bias,
             void* __restrict__ Cv, int M, int N, int K) {
  __shared__ __align__(16) unsigned short sh[65536];  // 131072 B

  int nwg = gridDim.x, bid = blockIdx.x, wg = bid;
  if ((nwg & 7) == 0) {              // bijective XCD swizzle (nwg % 8 == 0)
    int cpx = nwg >> 3;
    wg = (bid & 7) * cpx + (bid >> 3);
  }
  const int nbn = N >> 8;
  const int bm = wg / nbn, bn = wg - bm * nbn;

  const int tid = threadIdx.x, lane = tid & 63, w = tid >> 6;
  const int wm = w >> 2, wn = w & 3;          // wave -> (2M x 4N) grid
  const int fr = lane & 15, g = lane >> 4;

  // ---- staging setup: wave w owns 8 KiB = 8 chunks x 1 KiB (8 rows x 128 B) ----
  // waves 0-3 -> A rows [w*64, w*64+64); waves 4-7 -> B rows [(w-4)*64, ...)
  const int lr = lane >> 3;                        // row within chunk
  const int lb = ((lane & 7) << 4) ^ (lr << 4);    // pre-swizzled byte-in-row
  const unsigned short* gsrc = (w < 4)
      ? A  + (size_t)(bm * 256 + w * 64 + lr) * K + (lb >> 1)
      : Bt + (size_t)(bn * 256 + (w - 4) * 64 + lr) * K + (lb >> 1);
  const int ldsw = w * 8192;                       // wave chunk-0 byte offset in buffer

  // ---- fragment read offsets (bytes), XOR matches staging swizzle ----
  const int koff0 = (g * 16) ^ ((fr & 7) << 4);    // ksub 0
  const int koff1 = koff0 ^ 64;                    // ksub 1 (bit 6)

  f32x4 acc[8][4] = {};
  const int NT = K >> 6;                           // 16 K-tiles

  // prologue: stage tile 0 into buf 0
  {
    char* l0 = (char*)sh + ldsw;
#pragma unroll
    for (int c = 0; c < 8; ++c)
      load_lds16(gsrc + (size_t)c * 8 * K, l0 + c * 1024);
  }

  for (int t = 0; t < NT; ++t) {
    // issue next-tile stage; counted wait for current tile
    if (t + 1 < NT) {
      const unsigned short* sN = gsrc + (size_t)(t + 1) * 64;
      char* lN = (char*)sh + ((t + 1) & 1) * 65536 + ldsw;
#pragma unroll
      for (int c = 0; c < 8; ++c)
        load_lds16(sN + (size_t)c * 8 * K, lN + c * 1024);
      asm volatile("s_waitcnt vmcnt(8)" ::: "memory");
    } else {
      asm volatile("s_waitcnt vmcnt(0)" ::: "memory");
    }
    __builtin_amdgcn_sched_barrier(0);
    __builtin_amdgcn_s_barrier();                  // tile t visible to all waves

    const char* bufp = (const char*)sh + (t & 1) * 65536;
    const char* ap0 = bufp + (wm * 128 + fr) * 128;
    const char* bp0 = bufp + 32768 + (wn * 64 + fr) * 128;

#pragma unroll
    for (int q = 0; q < 4; ++q) {                  // quadrant (mh, nh)
      const int mh = q >> 1, nh = q & 1;
      short8 af[4][2], bf[2][2];
      const char* ap = ap0 + mh * 64 * 128;
      const char* bp = bp0 + nh * 32 * 128;
#pragma unroll
      for (int ii = 0; ii < 4; ++ii) {
        af[ii][0] = *(const short8*)(ap + ii * 2048 + koff0);
        af[ii][1] = *(const short8*)(ap + ii * 2048 + koff1);
      }
#pragma unroll
      for (int jj = 0; jj < 2; ++jj) {
        bf[jj][0] = *(const short8*)(bp + jj * 2048 + koff0);
        bf[jj][1] = *(const short8*)(bp + jj * 2048 + koff1);
      }
      __builtin_amdgcn_s_barrier();                // phase-align
      asm volatile("s_waitcnt lgkmcnt(0)" ::: "memory");
      __builtin_amdgcn_sched_barrier(0);           // rule 18: pin MFMA below wait
      __builtin_amdgcn_s_setprio(1);
#pragma unroll
      for (int s = 0; s < 2; ++s)
#pragma unroll
        for (int ii = 0; ii < 4; ++ii)
#pragma unroll
          for (int jj = 0; jj < 2; ++jj)
            acc[mh * 4 + ii][nh * 2 + jj] =
                MFMA_BF16(af[ii][s], bf[jj][s], acc[mh * 4 + ii][nh * 2 + jj]);
      __builtin_amdgcn_s_setprio(0);
      __builtin_amdgcn_s_barrier();                // end of phase
    }
  }

  // epilogue: C/D layout col = lane&15, row = (lane>>4)*4 + reg
  const int grow0 = bm * 256 + wm * 128 + g * 4;
  const int gcol0 = bn * 256 + wn * 64 + fr;
#pragma unroll
  for (int j = 0; j < 4; ++j) {
    const int gc = gcol0 + j * 16;
    const float bv_ = bias[gc];
#pragma unroll
    for (int i = 0; i < 8; ++i) {
      const int gr = grow0 + i * 16;
#pragma unroll
      for (int r = 0; r < 4; ++r) {
        float v = acc[i][j][r] + bv_;
        if (OUT_F32) ((float*)Cv)[(size_t)(gr + r) * N + gc] = v;
        else ((unsigned short*)Cv)[(size_t)(gr + r) * N + gc] = f2b(v);
      }
    }
  }
}

// ---------------- attention: one block per (patch, head) ----------------
// (unchanged from R3 — isolating the GEMM change this round)

__global__ __launch_bounds__(256)
void attn_k(const unsigned short* __restrict__ qkv, unsigned short* __restrict__ out) {
  const int bh = blockIdx.x;
  const int p = bh >> 4, h = bh & 15;
  const int tid = threadIdx.x, lane = tid & 63, wv = tid >> 6;
  const int fr = lane & 15, fks = (lane >> 4) << 3;

  __shared__ __align__(16) unsigned short vt[64][136];        // V^T [dim][token], +pad
  __shared__ __align__(16) unsigned short pls[4][32][136];    // per-wave P staging

  const size_t rowbase = (size_t)p * 128 * 3072;

  {
    const unsigned short* vsrc = qkv + rowbase + 2048 + (size_t)h * 64;
#pragma unroll
    for (int it = 0; it < 8; ++it) {
      int idx = tid + it * 256;
      int t = idx >> 4;
      int d4 = (idx & 15) << 2;
      ushort4 vv = *(const ushort4*)(vsrc + (size_t)t * 3072 + d4);
      vt[d4 + 0][t] = vv.x; vt[d4 + 1][t] = vv.y;
      vt[d4 + 2][t] = vv.z; vt[d4 + 3][t] = vv.w;
    }
  }

  short8 qf[2][2];
  {
    const unsigned short* qsrc = qkv + rowbase + (size_t)(wv * 32) * 3072 + h * 64;
#pragma unroll
    for (int mf = 0; mf < 2; ++mf)
#pragma unroll
      for (int kc = 0; kc < 2; ++kc)
        qf[mf][kc] = *(const short8*)(qsrc + (size_t)(mf * 16 + fr) * 3072 + kc * 32 + fks);
  }

  f32x4 s[2][8] = {};
  {
    const unsigned short* ksrc = qkv + rowbase + 1024 + (size_t)h * 64;
#pragma unroll
    for (int kc = 0; kc < 2; ++kc)
#pragma unroll
      for (int nf = 0; nf < 8; ++nf) {
        short8 kf = *(const short8*)(ksrc + (size_t)(nf * 16 + fr) * 3072 + kc * 32 + fks);
        s[0][nf] = MFMA_BF16(qf[0][kc], kf, s[0][nf]);
        s[1][nf] = MFMA_BF16(qf[1][kc], kf, s[1][nf]);
      }
  }
  __syncthreads();

  const float c0 = 0.125f * 1.44269504088896f;
  float sm[2][4];
#pragma unroll
  for (int mf = 0; mf < 2; ++mf)
#pragma unroll
    for (int r = 0; r < 4; ++r) {
      float m = s[mf][0][r];
#pragma unroll
      for (int nf = 1; nf < 8; ++nf) m = fmaxf(m, s[mf][nf][r]);
      m = fmaxf(m, __shfl_xor(m, 1));
      m = fmaxf(m, __shfl_xor(m, 2));
      m = fmaxf(m, __shfl_xor(m, 4));
      m = fmaxf(m, __shfl_xor(m, 8));
      float su = 0.f;
#pragma unroll
      for (int nf = 0; nf < 8; ++nf) {
        float e = exp2f((s[mf][nf][r] - m) * c0);
        s[mf][nf][r] = e;
        su += e;
      }
      su += __shfl_xor(su, 1);
      su += __shfl_xor(su, 2);
      su += __shfl_xor(su, 4);
      su += __shfl_xor(su, 8);
      sm[mf][r] = su;
    }

#pragma unroll
  for (int mf = 0; mf < 2; ++mf)
#pragma unroll
    for (int nf = 0; nf < 8; ++nf)
#pragma unroll
      for (int r = 0; r < 4; ++r)
        pls[wv][mf * 16 + ((lane >> 4) << 2) + r][nf * 16 + fr] = f2b(s[mf][nf][r]);

  f32x4 o[2][4] = {};
#pragma unroll
  for (int kc = 0; kc < 4; ++kc) {
    short8 pf0 = *(const short8*)&pls[wv][fr][kc * 32 + fks];
    short8 pf1 = *(const short8*)&pls[wv][16 + fr][kc * 32 + fks];
#pragma unroll
    for (int nf = 0; nf < 4; ++nf) {
      short8 vf = *(const short8*)&vt[nf * 16 + fr][kc * 32 + fks];
      o[0][nf] = MFMA_BF16(pf0, vf, o[0][nf]);
      o[1][nf] = MFMA_BF16(pf1, vf, o[1][nf]);
    }
  }

  unsigned short* obase = out + (size_t)(p * 128 + wv * 32) * 1024 + h * 64;
#pragma unroll
  for (int mf = 0; mf < 2; ++mf)
#pragma unroll
    for (int nf = 0; nf < 4; ++nf)
#pragma unroll
      for (int r = 0; r < 4; ++r) {
        int row = mf * 16 + ((lane >> 4) << 2) + r;
        float val = o[mf][nf][r] / sm[mf][r];
        obase[(size_t)row * 1024 + nf * 16 + fr] = f2b(val);
      }
}

// ---------------- launcher ----------------

extern "C" void kernel_launch(void* const* d_in, const int* in_sizes, int n_in,
                              void* d_out, int out_size, void* d_ws, size_t ws_size,
                              hipStream_t stream) {
  const float* x  = (const float*)d_in[0];
  // d_in[1] = coords, unused by reference
  const float* Wq = (const float*)d_in[2];
  const float* bq = (const float*)d_in[3];
  const float* Wk = (const float*)d_in[4];
  const float* bk = (const float*)d_in[5];
  const float* Wv = (const float*)d_in[6];
  const float* bv = (const float*)d_in[7];
  const float* Wo = (const float*)d_in[8];
  const float* bo = (const float*)d_in[9];

  char* ws = (char*)d_ws;
  unsigned short* xb   = (unsigned short*)(ws);
  unsigned short* wqkv = (unsigned short*)(ws + 67108864);
  unsigned short* wot  = (unsigned short*)(ws + 73400320);
  float*          bqkv = (float*)(ws + 75497472);
  unsigned short* qkv  = (unsigned short*)(ws + 75509760);

  cvt_x_k<<<2048, 256, 0, stream>>>(x, xb, (32768 * 1024) / 4);
  twk4<<<1024, 256, 0, stream>>>(Wq, Wk, Wv, Wo, wqkv, wot);
  fuse_bias_k<<<12, 256, 0, stream>>>(bq, bk, bv, bqkv);

  // QKV: [32768,1024] x [3072,1024]^T -> bf16 [32768,3072]; 128x12 tiles
  gemm256<false><<<1536, 512, 0, stream>>>(xb, wqkv, bqkv, qkv, 32768, 3072, 1024);
  // attention: 256 patches x 16 heads; writes bf16 [32768,1024] into xb
  attn_k<<<4096, 256, 0, stream>>>(qkv, xb);
  // O-proj: [32768,1024] x [1024,1024]^T + bo -> fp32 d_out; 128x4 tiles
  gemm256<true><<<512, 512, 0, stream>>>(xb, wot, bo, d_out, 32768, 1024, 1024);
}

// Round 5
// 641.714 us; speedup vs baseline: 1.1200x; 1.1200x over previous
//
#include <hip/hip_runtime.h>
#include <hip/hip_bf16.h>

// PatchedAttention on MI355X (gfx950).
// B=4, T=8192, D=1024, H=16, Dh=64, PATCH=128 -> M=32768 tokens, 256 patches.
// R5: gemm256 phase schedule fixed to 24 ds_read/wave/K-tile (register-held
//     operand halves, gray-code quadrants, counted lgkm, late ph4 read-ahead).
// Workspace layout (bytes):
//   xb   @ 0         : 67,108,864  (x bf16 [32768][1024]; reused as attn-out)
//   wqkv @ 67108864  :  6,291,456  (Wq|Wk|Wv transposed bf16 [3072][1024])
//   wot  @ 73400320  :  2,097,152  (Wo transposed bf16 [1024][1024])
//   bqkv @ 75497472  :     12,288  (fused bias f32 [3072])
//   qkv  @ 75509760  : 201,326,592 (QKV bf16 [32768][3072])

#define DEV static __device__ __forceinline__

typedef __attribute__((ext_vector_type(8))) short short8;   // 8 x bf16 (4 VGPR)
typedef __attribute__((ext_vector_type(4))) float f32x4;    // MFMA C/D frag

DEV unsigned short f2b(float f) {  // fp32 -> bf16 RNE
  unsigned u = __builtin_bit_cast(unsigned, f);
  u += 0x7fffu + ((u >> 16) & 1u);
  return (unsigned short)(u >> 16);
}

DEV void load_lds16(const void* g, void* l) {  // async global->LDS, 16B/lane
  __builtin_amdgcn_global_load_lds(
      (const __attribute__((address_space(1))) void*)g,
      (__attribute__((address_space(3))) void*)l, 16, 0, 0);
}

#define MFMA_BF16(a, b, c) __builtin_amdgcn_mfma_f32_16x16x32_bf16((a), (b), (c), 0, 0, 0)
#define SB0() __builtin_amdgcn_sched_barrier(0)
#define BAR() __builtin_amdgcn_s_barrier()

// ---------------- pre-pass kernels ----------------

__global__ void cvt_x_k(const float* __restrict__ x, unsigned short* __restrict__ xb, int n4) {
  int i = blockIdx.x * blockDim.x + threadIdx.x;
  int stride = gridDim.x * blockDim.x;
  for (; i < n4; i += stride) {
    float4 v = ((const float4*)x)[i];
    ushort4 o;
    o.x = f2b(v.x); o.y = f2b(v.y); o.z = f2b(v.z); o.w = f2b(v.w);
    ((ushort4*)xb)[i] = o;
  }
}

// 4x W [1024][1024] (k-major) fp32 -> Wt [1024][1024] (n-major, k contiguous) bf16.
__global__ void twk4(const float* __restrict__ W0, const float* __restrict__ W1,
                     const float* __restrict__ W2, const float* __restrict__ W3,
                     unsigned short* __restrict__ Dqkv, unsigned short* __restrict__ Dot) {
  __shared__ unsigned short tile[64][65];
  const int w = blockIdx.x >> 8;
  const int t = blockIdx.x & 255;
  const float* W = (w == 0) ? W0 : (w == 1) ? W1 : (w == 2) ? W2 : W3;
  unsigned short* Wt = (w == 3) ? Dot : Dqkv + (size_t)w * 1024 * 1024;
  int k0 = (t >> 4) << 6;
  int n0 = (t & 15) << 6;
  int tx = threadIdx.x & 63;
  int ty = threadIdx.x >> 6;
#pragma unroll
  for (int i = 0; i < 16; ++i) {
    int r = (i << 2) + ty;
    tile[r][tx] = f2b(W[(size_t)(k0 + r) * 1024 + n0 + tx]);
  }
  __syncthreads();
#pragma unroll
  for (int i = 0; i < 16; ++i) {
    int n = (i << 2) + ty;
    Wt[(size_t)(n0 + n) * 1024 + k0 + tx] = tile[tx][n];
  }
}

__global__ void fuse_bias_k(const float* __restrict__ bq, const float* __restrict__ bk,
                            const float* __restrict__ bv, float* __restrict__ bqkv) {
  int i = blockIdx.x * 256 + threadIdx.x;
  if (i < 1024) bqkv[i] = bq[i];
  else if (i < 2048) bqkv[i] = bk[i - 1024];
  else if (i < 3072) bqkv[i] = bv[i - 2048];
}

// ---- GEMM 256x256 tile, BK=64, 8 waves (2M x 4N), 4-phase schedule ----
// C[M,N] = A[M,K] * Bt[N,K]^T + bias.
// LDS: 2 K-tile buffers x (A 256x64 | B 256x64) bf16 = 131072 B -> 1 block/CU.
// Swizzle: phys byte-in-row = logical ^ ((row&7)<<4); staged via pre-swizzled
// per-lane GLOBAL source (linear DMA dest), read with same XOR (R4: conflicts=0).
// Per K-tile: 24 ds_read_b128/wave (A0:8, A1:8, B0:4, B1:4), held in registers
// across quadrants q00->q01->q11->q10 (gray code, one operand changes/phase):
//  ph1: stage t+1 (8 DMA); read B1; lgkm(4);  mfma(A0,B0)
//  ph2: read A1;                    lgkm(8);  mfma(A0,B1)
//  ph3: vmcnt(0)+bar [t+1 in LDS];  lgkm(0);  mfma(A1,B1)
//  ph4: mfma(A1,B0); then read next tile's A0,B0 (12) [reg reuse, SB0-pinned]

template <bool OUT_F32>
__global__ __launch_bounds__(512, 2)
void gemm256(const unsigned short* __restrict__ A,
             const unsigned short* __restrict__ Bt,
             const float* __restrict__ bias,
             void* __restrict__ Cv, int M, int N, int K) {
  __shared__ __align__(16) unsigned short sh[65536];  // 131072 B

  int nwg = gridDim.x, bid = blockIdx.x, wg = bid;
  if ((nwg & 7) == 0) {              // bijective XCD swizzle (nwg % 8 == 0)
    int cpx = nwg >> 3;
    wg = (bid & 7) * cpx + (bid >> 3);
  }
  const int nbn = N >> 8;
  const int bm = wg / nbn, bn = wg - bm * nbn;

  const int tid = threadIdx.x, lane = tid & 63, w = tid >> 6;
  const int wm = w >> 2, wn = w & 3;          // wave -> (2M x 4N) grid
  const int fr = lane & 15, g = lane >> 4;

  // staging: wave w owns 8 KiB = 8 chunks x (8 rows x 128 B)
  const int lr = lane >> 3;                        // row within chunk
  const int lb = ((lane & 7) << 4) ^ (lr << 4);    // pre-swizzled byte-in-row
  const unsigned short* gsrc = (w < 4)
      ? A  + (size_t)(bm * 256 + w * 64 + lr) * K + (lb >> 1)
      : Bt + (size_t)(bn * 256 + (w - 4) * 64 + lr) * K + (lb >> 1);
  const int ldsw = w * 8192;                       // wave chunk-0 byte offset in buffer

  // fragment read offsets (bytes); XOR matches staging swizzle
  const int koff0 = (g * 16) ^ ((fr & 7) << 4);    // ksub 0
  const int koff1 = koff0 ^ 64;                    // ksub 1

  f32x4 acc[8][4] = {};
  const int NT = K >> 6;                           // 16 K-tiles (K=1024)

  short8 a0[4][2], a1[4][2], b0[2][2], b1[2][2];

  // prologue: stage tile 0 into buf 0; read its A0,B0
  {
    char* l0 = (char*)sh + ldsw;
#pragma unroll
    for (int c = 0; c < 8; ++c)
      load_lds16(gsrc + (size_t)c * 8 * K, l0 + c * 1024);
    asm volatile("s_waitcnt vmcnt(0)" ::: "memory");
    BAR();
    const char* ap = (const char*)sh + (wm * 128 + fr) * 128;
    const char* bp = (const char*)sh + 32768 + (wn * 64 + fr) * 128;
#pragma unroll
    for (int ii = 0; ii < 4; ++ii) {
      a0[ii][0] = *(const short8*)(ap + ii * 2048 + koff0);
      a0[ii][1] = *(const short8*)(ap + ii * 2048 + koff1);
    }
#pragma unroll
    for (int jj = 0; jj < 2; ++jj) {
      b0[jj][0] = *(const short8*)(bp + jj * 2048 + koff0);
      b0[jj][1] = *(const short8*)(bp + jj * 2048 + koff1);
    }
  }

  for (int t = 0; t < NT; ++t) {
    const char* bufc = (const char*)sh + (t & 1) * 65536;
    const char* bufn = (const char*)sh + ((t + 1) & 1) * 65536;
    const char* apc = bufc + (wm * 128 + fr) * 128;
    const char* bpc = bufc + 32768 + (wn * 64 + fr) * 128;

    // ---- ph1: stage t+1; read B1; mfma(A0,B0) -> acc[0..3][0..1]
    if (t + 1 < NT) {
      const unsigned short* sN = gsrc + (size_t)(t + 1) * 64;
      char* lN = (char*)sh + ((t + 1) & 1) * 65536 + ldsw;
#pragma unroll
      for (int c = 0; c < 8; ++c)
        load_lds16(sN + (size_t)c * 8 * K, lN + c * 1024);
    }
#pragma unroll
    for (int jj = 0; jj < 2; ++jj) {
      b1[jj][0] = *(const short8*)(bpc + 32 * 128 + jj * 2048 + koff0);
      b1[jj][1] = *(const short8*)(bpc + 32 * 128 + jj * 2048 + koff1);
    }
    BAR();
    asm volatile("s_waitcnt lgkmcnt(4)" ::: "memory");  // a0,b0 ready (b1 pending)
    SB0();
    __builtin_amdgcn_s_setprio(1);
#pragma unroll
    for (int s = 0; s < 2; ++s)
#pragma unroll
      for (int ii = 0; ii < 4; ++ii)
#pragma unroll
        for (int jj = 0; jj < 2; ++jj)
          acc[ii][jj] = MFMA_BF16(a0[ii][s], b0[jj][s], acc[ii][jj]);
    __builtin_amdgcn_s_setprio(0);
    BAR();

    // ---- ph2: read A1; mfma(A0,B1) -> acc[0..3][2..3]
#pragma unroll
    for (int ii = 0; ii < 4; ++ii) {
      a1[ii][0] = *(const short8*)(apc + 64 * 128 + ii * 2048 + koff0);
      a1[ii][1] = *(const short8*)(apc + 64 * 128 + ii * 2048 + koff1);
    }
    BAR();
    asm volatile("s_waitcnt lgkmcnt(8)" ::: "memory");  // b1 ready (a1 pending)
    SB0();
    __builtin_amdgcn_s_setprio(1);
#pragma unroll
    for (int s = 0; s < 2; ++s)
#pragma unroll
      for (int ii = 0; ii < 4; ++ii)
#pragma unroll
        for (int jj = 0; jj < 2; ++jj)
          acc[ii][2 + jj] = MFMA_BF16(a0[ii][s], b1[jj][s], acc[ii][2 + jj]);
    __builtin_amdgcn_s_setprio(0);
    BAR();

    // ---- ph3: tile t+1 DMA drained; mfma(A1,B1) -> acc[4..7][2..3]
    asm volatile("s_waitcnt vmcnt(0)" ::: "memory");    // only t+1's 8 in flight
    BAR();                                              // buf[t+1] visible to all
    asm volatile("s_waitcnt lgkmcnt(0)" ::: "memory");  // a1 ready
    SB0();
    __builtin_amdgcn_s_setprio(1);
#pragma unroll
    for (int s = 0; s < 2; ++s)
#pragma unroll
      for (int ii = 0; ii < 4; ++ii)
#pragma unroll
        for (int jj = 0; jj < 2; ++jj)
          acc[4 + ii][2 + jj] = MFMA_BF16(a1[ii][s], b1[jj][s], acc[4 + ii][2 + jj]);
    __builtin_amdgcn_s_setprio(0);
    BAR();

    // ---- ph4: mfma(A1,B0) -> acc[4..7][0..1]; then read next A0,B0
    __builtin_amdgcn_s_setprio(1);
#pragma unroll
    for (int s = 0; s < 2; ++s)
#pragma unroll
      for (int ii = 0; ii < 4; ++ii)
#pragma unroll
        for (int jj = 0; jj < 2; ++jj)
          acc[4 + ii][jj] = MFMA_BF16(a1[ii][s], b0[jj][s], acc[4 + ii][jj]);
    __builtin_amdgcn_s_setprio(0);
    SB0();  // pin reads below mfma: allows a0/b0 register reuse (no double-buffer)
    if (t + 1 < NT) {
      const char* apn = bufn + (wm * 128 + fr) * 128;
      const char* bpn = bufn + 32768 + (wn * 64 + fr) * 128;
#pragma unroll
      for (int ii = 0; ii < 4; ++ii) {
        a0[ii][0] = *(const short8*)(apn + ii * 2048 + koff0);
        a0[ii][1] = *(const short8*)(apn + ii * 2048 + koff1);
      }
#pragma unroll
      for (int jj = 0; jj < 2; ++jj) {
        b0[jj][0] = *(const short8*)(bpn + jj * 2048 + koff0);
        b0[jj][1] = *(const short8*)(bpn + jj * 2048 + koff1);
      }
    }
    SB0();
    BAR();
  }

  // epilogue: C/D layout col = lane&15, row = (lane>>4)*4 + reg; j-inner so the
  // 4 x 32B store groups of one 128B line issue back-to-back (RMW amplification)
  const int grow0 = bm * 256 + wm * 128 + g * 4;
  const int gcol0 = bn * 256 + wn * 64 + fr;
  float bv_[4];
#pragma unroll
  for (int j = 0; j < 4; ++j) bv_[j] = bias[gcol0 + j * 16];
#pragma unroll
  for (int i = 0; i < 8; ++i) {
    const int gr = grow0 + i * 16;
#pragma unroll
    for (int r = 0; r < 4; ++r) {
#pragma unroll
      for (int j = 0; j < 4; ++j) {
        float v = acc[i][j][r] + bv_[j];
        if (OUT_F32) ((float*)Cv)[(size_t)(gr + r) * N + gcol0 + j * 16] = v;
        else ((unsigned short*)Cv)[(size_t)(gr + r) * N + gcol0 + j * 16] = f2b(v);
      }
    }
  }
}

// ---------------- attention: one block per (patch, head) ----------------
// (unchanged from R3/R4 — next round's target once its counters are visible)

__global__ __launch_bounds__(256)
void attn_k(const unsigned short* __restrict__ qkv, unsigned short* __restrict__ out) {
  const int bh = blockIdx.x;
  const int p = bh >> 4, h = bh & 15;
  const int tid = threadIdx.x, lane = tid & 63, wv = tid >> 6;
  const int fr = lane & 15, fks = (lane >> 4) << 3;

  __shared__ __align__(16) unsigned short vt[64][136];        // V^T [dim][token], +pad
  __shared__ __align__(16) unsigned short pls[4][32][136];    // per-wave P staging

  const size_t rowbase = (size_t)p * 128 * 3072;

  {
    const unsigned short* vsrc = qkv + rowbase + 2048 + (size_t)h * 64;
#pragma unroll
    for (int it = 0; it < 8; ++it) {
      int idx = tid + it * 256;
      int t = idx >> 4;
      int d4 = (idx & 15) << 2;
      ushort4 vv = *(const ushort4*)(vsrc + (size_t)t * 3072 + d4);
      vt[d4 + 0][t] = vv.x; vt[d4 + 1][t] = vv.y;
      vt[d4 + 2][t] = vv.z; vt[d4 + 3][t] = vv.w;
    }
  }

  short8 qf[2][2];
  {
    const unsigned short* qsrc = qkv + rowbase + (size_t)(wv * 32) * 3072 + h * 64;
#pragma unroll
    for (int mf = 0; mf < 2; ++mf)
#pragma unroll
      for (int kc = 0; kc < 2; ++kc)
        qf[mf][kc] = *(const short8*)(qsrc + (size_t)(mf * 16 + fr) * 3072 + kc * 32 + fks);
  }

  f32x4 s[2][8] = {};
  {
    const unsigned short* ksrc = qkv + rowbase + 1024 + (size_t)h * 64;
#pragma unroll
    for (int kc = 0; kc < 2; ++kc)
#pragma unroll
      for (int nf = 0; nf < 8; ++nf) {
        short8 kf = *(const short8*)(ksrc + (size_t)(nf * 16 + fr) * 3072 + kc * 32 + fks);
        s[0][nf] = MFMA_BF16(qf[0][kc], kf, s[0][nf]);
        s[1][nf] = MFMA_BF16(qf[1][kc], kf, s[1][nf]);
      }
  }
  __syncthreads();

  const float c0 = 0.125f * 1.44269504088896f;
  float sm[2][4];
#pragma unroll
  for (int mf = 0; mf < 2; ++mf)
#pragma unroll
    for (int r = 0; r < 4; ++r) {
      float m = s[mf][0][r];
#pragma unroll
      for (int nf = 1; nf < 8; ++nf) m = fmaxf(m, s[mf][nf][r]);
      m = fmaxf(m, __shfl_xor(m, 1));
      m = fmaxf(m, __shfl_xor(m, 2));
      m = fmaxf(m, __shfl_xor(m, 4));
      m = fmaxf(m, __shfl_xor(m, 8));
      float su = 0.f;
#pragma unroll
      for (int nf = 0; nf < 8; ++nf) {
        float e = exp2f((s[mf][nf][r] - m) * c0);
        s[mf][nf][r] = e;
        su += e;
      }
      su += __shfl_xor(su, 1);
      su += __shfl_xor(su, 2);
      su += __shfl_xor(su, 4);
      su += __shfl_xor(su, 8);
      sm[mf][r] = su;
    }

#pragma unroll
  for (int mf = 0; mf < 2; ++mf)
#pragma unroll
    for (int nf = 0; nf < 8; ++nf)
#pragma unroll
      for (int r = 0; r < 4; ++r)
        pls[wv][mf * 16 + ((lane >> 4) << 2) + r][nf * 16 + fr] = f2b(s[mf][nf][r]);

  f32x4 o[2][4] = {};
#pragma unroll
  for (int kc = 0; kc < 4; ++kc) {
    short8 pf0 = *(const short8*)&pls[wv][fr][kc * 32 + fks];
    short8 pf1 = *(const short8*)&pls[wv][16 + fr][kc * 32 + fks];
#pragma unroll
    for (int nf = 0; nf < 4; ++nf) {
      short8 vf = *(const short8*)&vt[nf * 16 + fr][kc * 32 + fks];
      o[0][nf] = MFMA_BF16(pf0, vf, o[0][nf]);
      o[1][nf] = MFMA_BF16(pf1, vf, o[1][nf]);
    }
  }

  unsigned short* obase = out + (size_t)(p * 128 + wv * 32) * 1024 + h * 64;
#pragma unroll
  for (int mf = 0; mf < 2; ++mf)
#pragma unroll
    for (int nf = 0; nf < 4; ++nf)
#pragma unroll
      for (int r = 0; r < 4; ++r) {
        int row = mf * 16 + ((lane >> 4) << 2) + r;
        float val = o[mf][nf][r] / sm[mf][r];
        obase[(size_t)row * 1024 + nf * 16 + fr] = f2b(val);
      }
}

// ---------------- launcher ----------------

extern "C" void kernel_launch(void* const* d_in, const int* in_sizes, int n_in,
                              void* d_out, int out_size, void* d_ws, size_t ws_size,
                              hipStream_t stream) {
  const float* x  = (const float*)d_in[0];
  // d_in[1] = coords, unused by reference
  const float* Wq = (const float*)d_in[2];
  const float* bq = (const float*)d_in[3];
  const float* Wk = (const float*)d_in[4];
  const float* bk = (const float*)d_in[5];
  const float* Wv = (const float*)d_in[6];
  const float* bv = (const float*)d_in[7];
  const float* Wo = (const float*)d_in[8];
  const float* bo = (const float*)d_in[9];

  char* ws = (char*)d_ws;
  unsigned short* xb   = (unsigned short*)(ws);
  unsigned short* wqkv = (unsigned short*)(ws + 67108864);
  unsigned short* wot  = (unsigned short*)(ws + 73400320);
  float*          bqkv = (float*)(ws + 75497472);
  unsigned short* qkv  = (unsigned short*)(ws + 75509760);

  cvt_x_k<<<2048, 256, 0, stream>>>(x, xb, (32768 * 1024) / 4);
  twk4<<<1024, 256, 0, stream>>>(Wq, Wk, Wv, Wo, wqkv, wot);
  fuse_bias_k<<<12, 256, 0, stream>>>(bq, bk, bv, bqkv);

  // QKV: [32768,1024] x [3072,1024]^T -> bf16 [32768,3072]; 128x12 tiles
  gemm256<false><<<1536, 512, 0, stream>>>(xb, wqkv, bqkv, qkv, 32768, 3072, 1024);
  // attention: 256 patches x 16 heads; writes bf16 [32768,1024] into xb
  attn_k<<<4096, 256, 0, stream>>>(qkv, xb);
  // O-proj: [32768,1024] x [1024,1024]^T + bo -> fp32 d_out; 128x4 tiles
  gemm256<true><<<512, 512, 0, stream>>>(xb, wot, bo, d_out, 32768, 1024, 1024);
}

// Round 6
// 631.142 us; speedup vs baseline: 1.1388x; 1.0167x over previous
//
#include <hip/hip_runtime.h>
#include <hip/hip_bf16.h>

// PatchedAttention on MI355X (gfx950).
// B=4, T=8192, D=1024, H=16, Dh=64, PATCH=128 -> M=32768 tokens, 256 patches.
// R6: gemm256 DMA pipeline deepened to 2 K-tiles in flight (stage t+2 at ph3,
//     counted vmcnt(8) instead of vmcnt(0) drain; lgkm(0) hoisted to ph2-end).
// Workspace layout (bytes):
//   xb   @ 0         : 67,108,864  (x bf16 [32768][1024]; reused as attn-out)
//   wqkv @ 67108864  :  6,291,456  (Wq|Wk|Wv transposed bf16 [3072][1024])
//   wot  @ 73400320  :  2,097,152  (Wo transposed bf16 [1024][1024])
//   bqkv @ 75497472  :     12,288  (fused bias f32 [3072])
//   qkv  @ 75509760  : 201,326,592 (QKV bf16 [32768][3072])

#define DEV static __device__ __forceinline__

typedef __attribute__((ext_vector_type(8))) short short8;   // 8 x bf16 (4 VGPR)
typedef __attribute__((ext_vector_type(4))) float f32x4;    // MFMA C/D frag

DEV unsigned short f2b(float f) {  // fp32 -> bf16 RNE
  unsigned u = __builtin_bit_cast(unsigned, f);
  u += 0x7fffu + ((u >> 16) & 1u);
  return (unsigned short)(u >> 16);
}

DEV void load_lds16(const void* g, void* l) {  // async global->LDS, 16B/lane
  __builtin_amdgcn_global_load_lds(
      (const __attribute__((address_space(1))) void*)g,
      (__attribute__((address_space(3))) void*)l, 16, 0, 0);
}

#define MFMA_BF16(a, b, c) __builtin_amdgcn_mfma_f32_16x16x32_bf16((a), (b), (c), 0, 0, 0)
#define SB0() __builtin_amdgcn_sched_barrier(0)
#define BAR() __builtin_amdgcn_s_barrier()

// ---------------- pre-pass kernels ----------------

__global__ void cvt_x_k(const float* __restrict__ x, unsigned short* __restrict__ xb, int n4) {
  int i = blockIdx.x * blockDim.x + threadIdx.x;
  int stride = gridDim.x * blockDim.x;
  for (; i < n4; i += stride) {
    float4 v = ((const float4*)x)[i];
    ushort4 o;
    o.x = f2b(v.x); o.y = f2b(v.y); o.z = f2b(v.z); o.w = f2b(v.w);
    ((ushort4*)xb)[i] = o;
  }
}

// 4x W [1024][1024] (k-major) fp32 -> Wt [1024][1024] (n-major, k contiguous) bf16.
__global__ void twk4(const float* __restrict__ W0, const float* __restrict__ W1,
                     const float* __restrict__ W2, const float* __restrict__ W3,
                     unsigned short* __restrict__ Dqkv, unsigned short* __restrict__ Dot) {
  __shared__ unsigned short tile[64][65];
  const int w = blockIdx.x >> 8;
  const int t = blockIdx.x & 255;
  const float* W = (w == 0) ? W0 : (w == 1) ? W1 : (w == 2) ? W2 : W3;
  unsigned short* Wt = (w == 3) ? Dot : Dqkv + (size_t)w * 1024 * 1024;
  int k0 = (t >> 4) << 6;
  int n0 = (t & 15) << 6;
  int tx = threadIdx.x & 63;
  int ty = threadIdx.x >> 6;
#pragma unroll
  for (int i = 0; i < 16; ++i) {
    int r = (i << 2) + ty;
    tile[r][tx] = f2b(W[(size_t)(k0 + r) * 1024 + n0 + tx]);
  }
  __syncthreads();
#pragma unroll
  for (int i = 0; i < 16; ++i) {
    int n = (i << 2) + ty;
    Wt[(size_t)(n0 + n) * 1024 + k0 + tx] = tile[tx][n];
  }
}

__global__ void fuse_bias_k(const float* __restrict__ bq, const float* __restrict__ bk,
                            const float* __restrict__ bv, float* __restrict__ bqkv) {
  int i = blockIdx.x * 256 + threadIdx.x;
  if (i < 1024) bqkv[i] = bq[i];
  else if (i < 2048) bqkv[i] = bk[i - 1024];
  else if (i < 3072) bqkv[i] = bv[i - 2048];
}

// ---- GEMM 256x256 tile, BK=64, 8 waves (2M x 4N), 4-phase schedule ----
// C[M,N] = A[M,K] * Bt[N,K]^T + bias.
// LDS: 2 K-tile buffers x (A 256x64 | B 256x64) bf16 = 131072 B -> 1 block/CU.
// Swizzle: phys byte-in-row = logical ^ ((row&7)<<4); staged via pre-swizzled
// per-lane GLOBAL source (linear DMA dest), read with same XOR (conflicts=0).
// R6 pipeline: 2 stages in flight. Per K-tile t (gray-code quadrants, 24
// ds_read_b128/wave/tile):
//  ph1: read B1(4);       BAR; lgkm(4) [a0,b0 ready]; MFMA(A0,B0); BAR
//  ph2: read A1(8);       BAR; lgkm(8) [b1 ready];    MFMA(A0,B1);
//       lgkm(0) [all bufc reads done] BAR            <- frees bufc for DMA
//  ph3: issue stage(t+2)->buf[t&1]; MFMA(A1,B1); vmcnt(8) [stage(t+1) done]; BAR
//  ph4: MFMA(A1,B0); read-ahead A0/B0 of t+1 from buf[(t+1)&1]; BAR
// Cover per stage ~5 phases (>900cyc HBM latency); vmcnt never drains to 0
// in steady state (T4).

template <bool OUT_F32>
__global__ __launch_bounds__(512, 2)
void gemm256(const unsigned short* __restrict__ A,
             const unsigned short* __restrict__ Bt,
             const float* __restrict__ bias,
             void* __restrict__ Cv, int M, int N, int K) {
  __shared__ __align__(16) unsigned short sh[65536];  // 131072 B

  int nwg = gridDim.x, bid = blockIdx.x, wg = bid;
  if ((nwg & 7) == 0) {              // bijective XCD swizzle (nwg % 8 == 0)
    int cpx = nwg >> 3;
    wg = (bid & 7) * cpx + (bid >> 3);
  }
  const int nbn = N >> 8;
  const int bm = wg / nbn, bn = wg - bm * nbn;

  const int tid = threadIdx.x, lane = tid & 63, w = tid >> 6;
  const int wm = w >> 2, wn = w & 3;          // wave -> (2M x 4N) grid
  const int fr = lane & 15, g = lane >> 4;

  // staging: wave w owns 8 KiB = 8 chunks x (8 rows x 128 B)
  const int lr = lane >> 3;                        // row within chunk
  const int lb = ((lane & 7) << 4) ^ (lr << 4);    // pre-swizzled byte-in-row
  const unsigned short* gsrc = (w < 4)
      ? A  + (size_t)(bm * 256 + w * 64 + lr) * K + (lb >> 1)
      : Bt + (size_t)(bn * 256 + (w - 4) * 64 + lr) * K + (lb >> 1);
  const int ldsw = w * 8192;                       // wave chunk-0 byte offset in buffer

  // fragment read offsets (bytes); XOR matches staging swizzle
  const int koff0 = (g * 16) ^ ((fr & 7) << 4);    // ksub 0
  const int koff1 = koff0 ^ 64;                    // ksub 1

  f32x4 acc[8][4] = {};
  const int NT = K >> 6;                           // 16 K-tiles (K=1024)

  short8 a0[4][2], a1[4][2], b0[2][2], b1[2][2];

  // prologue: stage tile 0 -> buf0 and tile 1 -> buf1; wait tile 0; read A0,B0
  {
    char* l0 = (char*)sh + ldsw;
    char* l1 = (char*)sh + 65536 + ldsw;
#pragma unroll
    for (int c = 0; c < 8; ++c)
      load_lds16(gsrc + (size_t)c * 8 * K, l0 + c * 1024);
#pragma unroll
    for (int c = 0; c < 8; ++c)
      load_lds16(gsrc + 64 + (size_t)c * 8 * K, l1 + c * 1024);
    asm volatile("s_waitcnt vmcnt(8)" ::: "memory");  // tile 0 landed
    BAR();
    const char* ap = (const char*)sh + (wm * 128 + fr) * 128;
    const char* bp = (const char*)sh + 32768 + (wn * 64 + fr) * 128;
#pragma unroll
    for (int ii = 0; ii < 4; ++ii) {
      a0[ii][0] = *(const short8*)(ap + ii * 2048 + koff0);
      a0[ii][1] = *(const short8*)(ap + ii * 2048 + koff1);
    }
#pragma unroll
    for (int jj = 0; jj < 2; ++jj) {
      b0[jj][0] = *(const short8*)(bp + jj * 2048 + koff0);
      b0[jj][1] = *(const short8*)(bp + jj * 2048 + koff1);
    }
  }

  for (int t = 0; t < NT; ++t) {
    const char* bufc = (const char*)sh + (t & 1) * 65536;
    const char* bufn = (const char*)sh + ((t + 1) & 1) * 65536;
    const char* apc = bufc + (wm * 128 + fr) * 128;
    const char* bpc = bufc + 32768 + (wn * 64 + fr) * 128;

    // ---- ph1: read B1; mfma(A0,B0) -> acc[0..3][0..1]
#pragma unroll
    for (int jj = 0; jj < 2; ++jj) {
      b1[jj][0] = *(const short8*)(bpc + 32 * 128 + jj * 2048 + koff0);
      b1[jj][1] = *(const short8*)(bpc + 32 * 128 + jj * 2048 + koff1);
    }
    BAR();
    asm volatile("s_waitcnt lgkmcnt(4)" ::: "memory");  // a0,b0 ready (b1 pending)
    SB0();
    __builtin_amdgcn_s_setprio(1);
#pragma unroll
    for (int s = 0; s < 2; ++s)
#pragma unroll
      for (int ii = 0; ii < 4; ++ii)
#pragma unroll
        for (int jj = 0; jj < 2; ++jj)
          acc[ii][jj] = MFMA_BF16(a0[ii][s], b0[jj][s], acc[ii][jj]);
    __builtin_amdgcn_s_setprio(0);
    BAR();

    // ---- ph2: read A1; mfma(A0,B1) -> acc[0..3][2..3]; drain all bufc reads
#pragma unroll
    for (int ii = 0; ii < 4; ++ii) {
      a1[ii][0] = *(const short8*)(apc + 64 * 128 + ii * 2048 + koff0);
      a1[ii][1] = *(const short8*)(apc + 64 * 128 + ii * 2048 + koff1);
    }
    BAR();
    asm volatile("s_waitcnt lgkmcnt(8)" ::: "memory");  // b1 ready (a1 pending)
    SB0();
    __builtin_amdgcn_s_setprio(1);
#pragma unroll
    for (int s = 0; s < 2; ++s)
#pragma unroll
      for (int ii = 0; ii < 4; ++ii)
#pragma unroll
        for (int jj = 0; jj < 2; ++jj)
          acc[ii][2 + jj] = MFMA_BF16(a0[ii][s], b1[jj][s], acc[ii][2 + jj]);
    __builtin_amdgcn_s_setprio(0);
    SB0();
    asm volatile("s_waitcnt lgkmcnt(0)" ::: "memory");  // a1 done; bufc read-free
    BAR();                                              // block-wide: bufc reusable

    // ---- ph3: issue stage(t+2) into bufc; mfma(A1,B1); counted vmcnt
    if (t + 2 < NT) {
      const unsigned short* sN = gsrc + (size_t)(t + 2) * 64;
      char* lN = (char*)sh + (t & 1) * 65536 + ldsw;
#pragma unroll
      for (int c = 0; c < 8; ++c)
        load_lds16(sN + (size_t)c * 8 * K, lN + c * 1024);
    }
    __builtin_amdgcn_s_setprio(1);
#pragma unroll
    for (int s = 0; s < 2; ++s)
#pragma unroll
      for (int ii = 0; ii < 4; ++ii)
#pragma unroll
        for (int jj = 0; jj < 2; ++jj)
          acc[4 + ii][2 + jj] = MFMA_BF16(a1[ii][s], b1[jj][s], acc[4 + ii][2 + jj]);
    __builtin_amdgcn_s_setprio(0);
    if (t + 2 < NT) {
      asm volatile("s_waitcnt vmcnt(8)" ::: "memory");  // stage(t+1) landed
    } else {
      asm volatile("s_waitcnt vmcnt(0)" ::: "memory");  // tail: full drain
    }
    BAR();                                              // buf[(t+1)&1] visible

    // ---- ph4: mfma(A1,B0) -> acc[4..7][0..1]; then read next A0,B0 from bufn
    __builtin_amdgcn_s_setprio(1);
#pragma unroll
    for (int s = 0; s < 2; ++s)
#pragma unroll
      for (int ii = 0; ii < 4; ++ii)
#pragma unroll
        for (int jj = 0; jj < 2; ++jj)
          acc[4 + ii][jj] = MFMA_BF16(a1[ii][s], b0[jj][s], acc[4 + ii][jj]);
    __builtin_amdgcn_s_setprio(0);
    SB0();  // pin reads below mfma: allows a0/b0 register reuse (no double-buffer)
    if (t + 1 < NT) {
      const char* apn = bufn + (wm * 128 + fr) * 128;
      const char* bpn = bufn + 32768 + (wn * 64 + fr) * 128;
#pragma unroll
      for (int ii = 0; ii < 4; ++ii) {
        a0[ii][0] = *(const short8*)(apn + ii * 2048 + koff0);
        a0[ii][1] = *(const short8*)(apn + ii * 2048 + koff1);
      }
#pragma unroll
      for (int jj = 0; jj < 2; ++jj) {
        b0[jj][0] = *(const short8*)(bpn + jj * 2048 + koff0);
        b0[jj][1] = *(const short8*)(bpn + jj * 2048 + koff1);
      }
    }
    SB0();
    BAR();
  }

  // epilogue: C/D layout col = lane&15, row = (lane>>4)*4 + reg; j-inner so the
  // 4 x 32B store groups of one 128B line issue back-to-back (RMW amplification)
  const int grow0 = bm * 256 + wm * 128 + g * 4;
  const int gcol0 = bn * 256 + wn * 64 + fr;
  float bv_[4];
#pragma unroll
  for (int j = 0; j < 4; ++j) bv_[j] = bias[gcol0 + j * 16];
#pragma unroll
  for (int i = 0; i < 8; ++i) {
    const int gr = grow0 + i * 16;
#pragma unroll
    for (int r = 0; r < 4; ++r) {
#pragma unroll
      for (int j = 0; j < 4; ++j) {
        float v = acc[i][j][r] + bv_[j];
        if (OUT_F32) ((float*)Cv)[(size_t)(gr + r) * N + gcol0 + j * 16] = v;
        else ((unsigned short*)Cv)[(size_t)(gr + r) * N + gcol0 + j * 16] = f2b(v);
      }
    }
  }
}

// ---------------- attention: one block per (patch, head) ----------------
// (unchanged — isolating the GEMM pipeline change this round)

__global__ __launch_bounds__(256)
void attn_k(const unsigned short* __restrict__ qkv, unsigned short* __restrict__ out) {
  const int bh = blockIdx.x;
  const int p = bh >> 4, h = bh & 15;
  const int tid = threadIdx.x, lane = tid & 63, wv = tid >> 6;
  const int fr = lane & 15, fks = (lane >> 4) << 3;

  __shared__ __align__(16) unsigned short vt[64][136];        // V^T [dim][token], +pad
  __shared__ __align__(16) unsigned short pls[4][32][136];    // per-wave P staging

  const size_t rowbase = (size_t)p * 128 * 3072;

  {
    const unsigned short* vsrc = qkv + rowbase + 2048 + (size_t)h * 64;
#pragma unroll
    for (int it = 0; it < 8; ++it) {
      int idx = tid + it * 256;
      int t = idx >> 4;
      int d4 = (idx & 15) << 2;
      ushort4 vv = *(const ushort4*)(vsrc + (size_t)t * 3072 + d4);
      vt[d4 + 0][t] = vv.x; vt[d4 + 1][t] = vv.y;
      vt[d4 + 2][t] = vv.z; vt[d4 + 3][t] = vv.w;
    }
  }

  short8 qf[2][2];
  {
    const unsigned short* qsrc = qkv + rowbase + (size_t)(wv * 32) * 3072 + h * 64;
#pragma unroll
    for (int mf = 0; mf < 2; ++mf)
#pragma unroll
      for (int kc = 0; kc < 2; ++kc)
        qf[mf][kc] = *(const short8*)(qsrc + (size_t)(mf * 16 + fr) * 3072 + kc * 32 + fks);
  }

  f32x4 s[2][8] = {};
  {
    const unsigned short* ksrc = qkv + rowbase + 1024 + (size_t)h * 64;
#pragma unroll
    for (int kc = 0; kc < 2; ++kc)
#pragma unroll
      for (int nf = 0; nf < 8; ++nf) {
        short8 kf = *(const short8*)(ksrc + (size_t)(nf * 16 + fr) * 3072 + kc * 32 + fks);
        s[0][nf] = MFMA_BF16(qf[0][kc], kf, s[0][nf]);
        s[1][nf] = MFMA_BF16(qf[1][kc], kf, s[1][nf]);
      }
  }
  __syncthreads();

  const float c0 = 0.125f * 1.44269504088896f;
  float sm[2][4];
#pragma unroll
  for (int mf = 0; mf < 2; ++mf)
#pragma unroll
    for (int r = 0; r < 4; ++r) {
      float m = s[mf][0][r];
#pragma unroll
      for (int nf = 1; nf < 8; ++nf) m = fmaxf(m, s[mf][nf][r]);
      m = fmaxf(m, __shfl_xor(m, 1));
      m = fmaxf(m, __shfl_xor(m, 2));
      m = fmaxf(m, __shfl_xor(m, 4));
      m = fmaxf(m, __shfl_xor(m, 8));
      float su = 0.f;
#pragma unroll
      for (int nf = 0; nf < 8; ++nf) {
        float e = exp2f((s[mf][nf][r] - m) * c0);
        s[mf][nf][r] = e;
        su += e;
      }
      su += __shfl_xor(su, 1);
      su += __shfl_xor(su, 2);
      su += __shfl_xor(su, 4);
      su += __shfl_xor(su, 8);
      sm[mf][r] = su;
    }

#pragma unroll
  for (int mf = 0; mf < 2; ++mf)
#pragma unroll
    for (int nf = 0; nf < 8; ++nf)
#pragma unroll
      for (int r = 0; r < 4; ++r)
        pls[wv][mf * 16 + ((lane >> 4) << 2) + r][nf * 16 + fr] = f2b(s[mf][nf][r]);

  f32x4 o[2][4] = {};
#pragma unroll
  for (int kc = 0; kc < 4; ++kc) {
    short8 pf0 = *(const short8*)&pls[wv][fr][kc * 32 + fks];
    short8 pf1 = *(const short8*)&pls[wv][16 + fr][kc * 32 + fks];
#pragma unroll
    for (int nf = 0; nf < 4; ++nf) {
      short8 vf = *(const short8*)&vt[nf * 16 + fr][kc * 32 + fks];
      o[0][nf] = MFMA_BF16(pf0, vf, o[0][nf]);
      o[1][nf] = MFMA_BF16(pf1, vf, o[1][nf]);
    }
  }

  unsigned short* obase = out + (size_t)(p * 128 + wv * 32) * 1024 + h * 64;
#pragma unroll
  for (int mf = 0; mf < 2; ++mf)
#pragma unroll
    for (int nf = 0; nf < 4; ++nf)
#pragma unroll
      for (int r = 0; r < 4; ++r) {
        int row = mf * 16 + ((lane >> 4) << 2) + r;
        float val = o[mf][nf][r] / sm[mf][r];
        obase[(size_t)row * 1024 + nf * 16 + fr] = f2b(val);
      }
}

// ---------------- launcher ----------------

extern "C" void kernel_launch(void* const* d_in, const int* in_sizes, int n_in,
                              void* d_out, int out_size, void* d_ws, size_t ws_size,
                              hipStream_t stream) {
  const float* x  = (const float*)d_in[0];
  // d_in[1] = coords, unused by reference
  const float* Wq = (const float*)d_in[2];
  const float* bq = (const float*)d_in[3];
  const float* Wk = (const float*)d_in[4];
  const float* bk = (const float*)d_in[5];
  const float* Wv = (const float*)d_in[6];
  const float* bv = (const float*)d_in[7];
  const float* Wo = (const float*)d_in[8];
  const float* bo = (const float*)d_in[9];

  char* ws = (char*)d_ws;
  unsigned short* xb   = (unsigned short*)(ws);
  unsigned short* wqkv = (unsigned short*)(ws + 67108864);
  unsigned short* wot  = (unsigned short*)(ws + 73400320);
  float*          bqkv = (float*)(ws + 75497472);
  unsigned short* qkv  = (unsigned short*)(ws + 75509760);

  cvt_x_k<<<2048, 256, 0, stream>>>(x, xb, (32768 * 1024) / 4);
  twk4<<<1024, 256, 0, stream>>>(Wq, Wk, Wv, Wo, wqkv, wot);
  fuse_bias_k<<<12, 256, 0, stream>>>(bq, bk, bv, bqkv);

  // QKV: [32768,1024] x [3072,1024]^T -> bf16 [32768,3072]; 128x12 tiles
  gemm256<false><<<1536, 512, 0, stream>>>(xb, wqkv, bqkv, qkv, 32768, 3072, 1024);
  // attention: 256 patches x 16 heads; writes bf16 [32768,1024] into xb
  attn_k<<<4096, 256, 0, stream>>>(qkv, xb);
  // O-proj: [32768,1024] x [1024,1024]^T + bo -> fp32 d_out; 128x4 tiles
  gemm256<true><<<512, 512, 0, stream>>>(xb, wot, bo, d_out, 32768, 1024, 1024);
}

// Round 7
// 625.254 us; speedup vs baseline: 1.1495x; 1.0094x over previous
//
#include <hip/hip_runtime.h>
#include <hip/hip_bf16.h>

// PatchedAttention on MI355X (gfx950).
// B=4, T=8192, D=1024, H=16, Dh=64, PATCH=128 -> M=32768 tokens, 256 patches.
// R7: attn_k rewritten: 32x32x16 MFMA swapped QK^T (S^T=K*Q^T), in-register
//     softmax (1 shfl), cvt_pk+permlane32_swap P->A-frag (no P LDS roundtrip),
//     vectorized V^T staging. GEMMs unchanged from R6.
// Workspace layout (bytes):
//   xb   @ 0         : 67,108,864  (x bf16 [32768][1024]; reused as attn-out)
//   wqkv @ 67108864  :  6,291,456  (Wq|Wk|Wv transposed bf16 [3072][1024])
//   wot  @ 73400320  :  2,097,152  (Wo transposed bf16 [1024][1024])
//   bqkv @ 75497472  :     12,288  (fused bias f32 [3072])
//   qkv  @ 75509760  : 201,326,592 (QKV bf16 [32768][3072])

#define DEV static __device__ __forceinline__

typedef __attribute__((ext_vector_type(8))) short short8;   // 8 x bf16 (4 VGPR)
typedef __attribute__((ext_vector_type(4))) float f32x4;    // 16x16 C/D frag
typedef __attribute__((ext_vector_type(16))) float f32x16;  // 32x32 C/D frag

DEV unsigned short f2b(float f) {  // fp32 -> bf16 RNE
  unsigned u = __builtin_bit_cast(unsigned, f);
  u += 0x7fffu + ((u >> 16) & 1u);
  return (unsigned short)(u >> 16);
}

DEV unsigned cvtpk(float lo, float hi) {  // pack 2xf32 -> 2xbf16 in one dword
  unsigned r;
  asm("v_cvt_pk_bf16_f32 %0, %1, %2" : "=v"(r) : "v"(lo), "v"(hi));
  return r;
}

DEV void load_lds16(const void* g, void* l) {  // async global->LDS, 16B/lane
  __builtin_amdgcn_global_load_lds(
      (const __attribute__((address_space(1))) void*)g,
      (__attribute__((address_space(3))) void*)l, 16, 0, 0);
}

#define MFMA_BF16(a, b, c) __builtin_amdgcn_mfma_f32_16x16x32_bf16((a), (b), (c), 0, 0, 0)
#define MFMA32_BF16(a, b, c) __builtin_amdgcn_mfma_f32_32x32x16_bf16((a), (b), (c), 0, 0, 0)
#define SB0() __builtin_amdgcn_sched_barrier(0)
#define BAR() __builtin_amdgcn_s_barrier()

// ---------------- pre-pass kernels ----------------

__global__ void cvt_x_k(const float* __restrict__ x, unsigned short* __restrict__ xb, int n4) {
  int i = blockIdx.x * blockDim.x + threadIdx.x;
  int stride = gridDim.x * blockDim.x;
  for (; i < n4; i += stride) {
    float4 v = ((const float4*)x)[i];
    ushort4 o;
    o.x = f2b(v.x); o.y = f2b(v.y); o.z = f2b(v.z); o.w = f2b(v.w);
    ((ushort4*)xb)[i] = o;
  }
}

// 4x W [1024][1024] (k-major) fp32 -> Wt [1024][1024] (n-major, k contiguous) bf16.
__global__ void twk4(const float* __restrict__ W0, const float* __restrict__ W1,
                     const float* __restrict__ W2, const float* __restrict__ W3,
                     unsigned short* __restrict__ Dqkv, unsigned short* __restrict__ Dot) {
  __shared__ unsigned short tile[64][65];
  const int w = blockIdx.x >> 8;
  const int t = blockIdx.x & 255;
  const float* W = (w == 0) ? W0 : (w == 1) ? W1 : (w == 2) ? W2 : W3;
  unsigned short* Wt = (w == 3) ? Dot : Dqkv + (size_t)w * 1024 * 1024;
  int k0 = (t >> 4) << 6;
  int n0 = (t & 15) << 6;
  int tx = threadIdx.x & 63;
  int ty = threadIdx.x >> 6;
#pragma unroll
  for (int i = 0; i < 16; ++i) {
    int r = (i << 2) + ty;
    tile[r][tx] = f2b(W[(size_t)(k0 + r) * 1024 + n0 + tx]);
  }
  __syncthreads();
#pragma unroll
  for (int i = 0; i < 16; ++i) {
    int n = (i << 2) + ty;
    Wt[(size_t)(n0 + n) * 1024 + k0 + tx] = tile[tx][n];
  }
}

__global__ void fuse_bias_k(const float* __restrict__ bq, const float* __restrict__ bk,
                            const float* __restrict__ bv, float* __restrict__ bqkv) {
  int i = blockIdx.x * 256 + threadIdx.x;
  if (i < 1024) bqkv[i] = bq[i];
  else if (i < 2048) bqkv[i] = bk[i - 1024];
  else if (i < 3072) bqkv[i] = bv[i - 2048];
}

// ---- GEMM 256x256 tile, BK=64, 8 waves (2M x 4N), 4-phase schedule (R6) ----

template <bool OUT_F32>
__global__ __launch_bounds__(512, 2)
void gemm256(const unsigned short* __restrict__ A,
             const unsigned short* __restrict__ Bt,
             const float* __restrict__ bias,
             void* __restrict__ Cv, int M, int N, int K) {
  __shared__ __align__(16) unsigned short sh[65536];  // 131072 B

  int nwg = gridDim.x, bid = blockIdx.x, wg = bid;
  if ((nwg & 7) == 0) {              // bijective XCD swizzle (nwg % 8 == 0)
    int cpx = nwg >> 3;
    wg = (bid & 7) * cpx + (bid >> 3);
  }
  const int nbn = N >> 8;
  const int bm = wg / nbn, bn = wg - bm * nbn;

  const int tid = threadIdx.x, lane = tid & 63, w = tid >> 6;
  const int wm = w >> 2, wn = w & 3;          // wave -> (2M x 4N) grid
  const int fr = lane & 15, g = lane >> 4;

  // staging: wave w owns 8 KiB = 8 chunks x (8 rows x 128 B)
  const int lr = lane >> 3;                        // row within chunk
  const int lb = ((lane & 7) << 4) ^ (lr << 4);    // pre-swizzled byte-in-row
  const unsigned short* gsrc = (w < 4)
      ? A  + (size_t)(bm * 256 + w * 64 + lr) * K + (lb >> 1)
      : Bt + (size_t)(bn * 256 + (w - 4) * 64 + lr) * K + (lb >> 1);
  const int ldsw = w * 8192;                       // wave chunk-0 byte offset in buffer

  // fragment read offsets (bytes); XOR matches staging swizzle
  const int koff0 = (g * 16) ^ ((fr & 7) << 4);    // ksub 0
  const int koff1 = koff0 ^ 64;                    // ksub 1

  f32x4 acc[8][4] = {};
  const int NT = K >> 6;                           // 16 K-tiles (K=1024)

  short8 a0[4][2], a1[4][2], b0[2][2], b1[2][2];

  // prologue: stage tile 0 -> buf0 and tile 1 -> buf1; wait tile 0; read A0,B0
  {
    char* l0 = (char*)sh + ldsw;
    char* l1 = (char*)sh + 65536 + ldsw;
#pragma unroll
    for (int c = 0; c < 8; ++c)
      load_lds16(gsrc + (size_t)c * 8 * K, l0 + c * 1024);
#pragma unroll
    for (int c = 0; c < 8; ++c)
      load_lds16(gsrc + 64 + (size_t)c * 8 * K, l1 + c * 1024);
    asm volatile("s_waitcnt vmcnt(8)" ::: "memory");  // tile 0 landed
    BAR();
    const char* ap = (const char*)sh + (wm * 128 + fr) * 128;
    const char* bp = (const char*)sh + 32768 + (wn * 64 + fr) * 128;
#pragma unroll
    for (int ii = 0; ii < 4; ++ii) {
      a0[ii][0] = *(const short8*)(ap + ii * 2048 + koff0);
      a0[ii][1] = *(const short8*)(ap + ii * 2048 + koff1);
    }
#pragma unroll
    for (int jj = 0; jj < 2; ++jj) {
      b0[jj][0] = *(const short8*)(bp + jj * 2048 + koff0);
      b0[jj][1] = *(const short8*)(bp + jj * 2048 + koff1);
    }
  }

  for (int t = 0; t < NT; ++t) {
    const char* bufc = (const char*)sh + (t & 1) * 65536;
    const char* bufn = (const char*)sh + ((t + 1) & 1) * 65536;
    const char* apc = bufc + (wm * 128 + fr) * 128;
    const char* bpc = bufc + 32768 + (wn * 64 + fr) * 128;

    // ---- ph1: read B1; mfma(A0,B0)
#pragma unroll
    for (int jj = 0; jj < 2; ++jj) {
      b1[jj][0] = *(const short8*)(bpc + 32 * 128 + jj * 2048 + koff0);
      b1[jj][1] = *(const short8*)(bpc + 32 * 128 + jj * 2048 + koff1);
    }
    BAR();
    asm volatile("s_waitcnt lgkmcnt(4)" ::: "memory");
    SB0();
    __builtin_amdgcn_s_setprio(1);
#pragma unroll
    for (int s = 0; s < 2; ++s)
#pragma unroll
      for (int ii = 0; ii < 4; ++ii)
#pragma unroll
        for (int jj = 0; jj < 2; ++jj)
          acc[ii][jj] = MFMA_BF16(a0[ii][s], b0[jj][s], acc[ii][jj]);
    __builtin_amdgcn_s_setprio(0);
    BAR();

    // ---- ph2: read A1; mfma(A0,B1); drain all bufc reads
#pragma unroll
    for (int ii = 0; ii < 4; ++ii) {
      a1[ii][0] = *(const short8*)(apc + 64 * 128 + ii * 2048 + koff0);
      a1[ii][1] = *(const short8*)(apc + 64 * 128 + ii * 2048 + koff1);
    }
    BAR();
    asm volatile("s_waitcnt lgkmcnt(8)" ::: "memory");
    SB0();
    __builtin_amdgcn_s_setprio(1);
#pragma unroll
    for (int s = 0; s < 2; ++s)
#pragma unroll
      for (int ii = 0; ii < 4; ++ii)
#pragma unroll
        for (int jj = 0; jj < 2; ++jj)
          acc[ii][2 + jj] = MFMA_BF16(a0[ii][s], b1[jj][s], acc[ii][2 + jj]);
    __builtin_amdgcn_s_setprio(0);
    SB0();
    asm volatile("s_waitcnt lgkmcnt(0)" ::: "memory");
    BAR();                                              // bufc reusable

    // ---- ph3: issue stage(t+2) into bufc; mfma(A1,B1); counted vmcnt
    if (t + 2 < NT) {
      const unsigned short* sN = gsrc + (size_t)(t + 2) * 64;
      char* lN = (char*)sh + (t & 1) * 65536 + ldsw;
#pragma unroll
      for (int c = 0; c < 8; ++c)
        load_lds16(sN + (size_t)c * 8 * K, lN + c * 1024);
    }
    __builtin_amdgcn_s_setprio(1);
#pragma unroll
    for (int s = 0; s < 2; ++s)
#pragma unroll
      for (int ii = 0; ii < 4; ++ii)
#pragma unroll
        for (int jj = 0; jj < 2; ++jj)
          acc[4 + ii][2 + jj] = MFMA_BF16(a1[ii][s], b1[jj][s], acc[4 + ii][2 + jj]);
    __builtin_amdgcn_s_setprio(0);
    if (t + 2 < NT) {
      asm volatile("s_waitcnt vmcnt(8)" ::: "memory");  // stage(t+1) landed
    } else {
      asm volatile("s_waitcnt vmcnt(0)" ::: "memory");
    }
    BAR();                                              // buf[(t+1)&1] visible

    // ---- ph4: mfma(A1,B0); then read next A0,B0 from bufn
    __builtin_amdgcn_s_setprio(1);
#pragma unroll
    for (int s = 0; s < 2; ++s)
#pragma unroll
      for (int ii = 0; ii < 4; ++ii)
#pragma unroll
        for (int jj = 0; jj < 2; ++jj)
          acc[4 + ii][jj] = MFMA_BF16(a1[ii][s], b0[jj][s], acc[4 + ii][jj]);
    __builtin_amdgcn_s_setprio(0);
    SB0();
    if (t + 1 < NT) {
      const char* apn = bufn + (wm * 128 + fr) * 128;
      const char* bpn = bufn + 32768 + (wn * 64 + fr) * 128;
#pragma unroll
      for (int ii = 0; ii < 4; ++ii) {
        a0[ii][0] = *(const short8*)(apn + ii * 2048 + koff0);
        a0[ii][1] = *(const short8*)(apn + ii * 2048 + koff1);
      }
#pragma unroll
      for (int jj = 0; jj < 2; ++jj) {
        b0[jj][0] = *(const short8*)(bpn + jj * 2048 + koff0);
        b0[jj][1] = *(const short8*)(bpn + jj * 2048 + koff1);
      }
    }
    SB0();
    BAR();
  }

  // epilogue: j-inner stores (full 128B lines per store group)
  const int grow0 = bm * 256 + wm * 128 + g * 4;
  const int gcol0 = bn * 256 + wn * 64 + fr;
  float bv_[4];
#pragma unroll
  for (int j = 0; j < 4; ++j) bv_[j] = bias[gcol0 + j * 16];
#pragma unroll
  for (int i = 0; i < 8; ++i) {
    const int gr = grow0 + i * 16;
#pragma unroll
    for (int r = 0; r < 4; ++r) {
#pragma unroll
      for (int j = 0; j < 4; ++j) {
        float v = acc[i][j][r] + bv_[j];
        if (OUT_F32) ((float*)Cv)[(size_t)(gr + r) * N + gcol0 + j * 16] = v;
        else ((unsigned short*)Cv)[(size_t)(gr + r) * N + gcol0 + j * 16] = f2b(v);
      }
    }
  }
}

// ---------------- attention (R7): one block per (patch, head), 4 waves ----
// Wave wv owns q-rows [wv*32, wv*32+32). 32x32x16 MFMA, swapped operands:
//   S^T[128k x 32q] = mfma(A=K, B=Q)  -> lane holds q = lane&31, 64 of 128 k
//   (C layout: col=lane&31, row(reg r)=(r&3)+8*(r>>2)+4*(lane>>5) [m74/m101])
// softmax: 63 in-lane ops + 1 shfl_xor(32); 1/sum folded into P.
// P -> PV A-frags via cvt_pk + v_permlane32_swap (T12); no P LDS roundtrip.
// PV: O = mfma(A=P, B=V) with V^T staged in LDS (vectorized b64 writes).

__global__ __launch_bounds__(256)
void attn_k(const unsigned short* __restrict__ qkv, unsigned short* __restrict__ out) {
  const int bh = blockIdx.x;
  const int p = bh >> 4, h = bh & 15;
  const int tid = threadIdx.x, lane = tid & 63, wv = tid >> 6;
  const int c = lane & 31, hl = lane >> 5;

  __shared__ __align__(16) unsigned short vt[64][136];  // V^T [d][tok], 272B rows

  const size_t rowbase = (size_t)p * 128 * 3072;

  // ---- stage V transposed, vectorized: 2 (4tok x 4d) blocks per thread
  {
    const unsigned short* vsrc = qkv + rowbase + 2048 + (size_t)h * 64;
#pragma unroll
    for (int bb = 0; bb < 2; ++bb) {
      int b = bb * 256 + tid;
      int tg = b & 31, dg = b >> 5;   // tok-group of 4, d-group of 4
      ushort4 ld[4];
#pragma unroll
      for (int i = 0; i < 4; ++i)
        ld[i] = *(const ushort4*)(vsrc + (size_t)(tg * 4 + i) * 3072 + dg * 4);
#pragma unroll
      for (int j = 0; j < 4; ++j) {
        ushort4 wr;
        wr.x = ((const unsigned short*)&ld[0])[j];
        wr.y = ((const unsigned short*)&ld[1])[j];
        wr.z = ((const unsigned short*)&ld[2])[j];
        wr.w = ((const unsigned short*)&ld[3])[j];
        *(ushort4*)&vt[dg * 4 + j][tg * 4] = wr;
      }
    }
  }

  // ---- Q as B-frags: Q[q=wv*32+c][d = kc*16 + hl*8 + 0..7]
  short8 qf[4];
  {
    const unsigned short* qsrc = qkv + rowbase + (size_t)(wv * 32 + c) * 3072 + h * 64;
#pragma unroll
    for (int kc = 0; kc < 4; ++kc)
      qf[kc] = *(const short8*)(qsrc + kc * 16 + hl * 8);
  }

  // ---- S^T = K Q^T: st[kf] covers tokens [kf*32, kf*32+32)
  f32x16 st[4] = {};
  {
    const unsigned short* ksrc = qkv + rowbase + 1024 + (size_t)h * 64;
#pragma unroll
    for (int kf = 0; kf < 4; ++kf) {
      const unsigned short* kr = ksrc + (size_t)(kf * 32 + c) * 3072 + hl * 8;
      short8 kfr[4];
#pragma unroll
      for (int kc = 0; kc < 4; ++kc) kfr[kc] = *(const short8*)(kr + kc * 16);
#pragma unroll
      for (int kc = 0; kc < 4; ++kc)
        st[kf] = MFMA32_BF16(kfr[kc], qf[kc], st[kf]);
    }
  }

  // ---- softmax along k (per q-row = per lane + partner lane^32)
  const float c0 = 0.125f * 1.44269504088896f;  // scale * log2(e)
  float m = st[0][0];
#pragma unroll
  for (int kf = 0; kf < 4; ++kf)
#pragma unroll
    for (int r = 0; r < 16; ++r) m = fmaxf(m, st[kf][r]);
  m = fmaxf(m, __shfl_xor(m, 32));
  float su = 0.f;
#pragma unroll
  for (int kf = 0; kf < 4; ++kf)
#pragma unroll
    for (int r = 0; r < 16; ++r) {
      float e = exp2f((st[kf][r] - m) * c0);
      st[kf][r] = e;
      su += e;
    }
  su += __shfl_xor(su, 32);
  const float inv = 1.0f / su;

  __syncthreads();  // vt staged (V-store latency hidden under QK^T + softmax)

  // ---- PV: O[32q x 64d] = P V ; 8 k-steps of 16, 2 d-frags
  // step s: A-frag k = 16s + 8*hl + j. Source rows a..a+3 (a=8*(s&1)) of st[s>>1]:
  //   lanes<32 need [own r(a..a+3) | (lane+32) r(a..a+3)]
  //   lanes>=32 need [(lane-32) r(a+4..a+7) | own r(a+4..a+7)]
  // permlane32_swap(LO,HI): LO'=[LO(0-31)|HI(0-31)] = dword_i ; HI'=[LO(32-63)|HI(32-63)] = dword_{i+2}
  f32x16 ov[2] = {};
#pragma unroll
  for (int s = 0; s < 8; ++s) {
    const int kf = s >> 1, a = (s & 1) * 8;
    unsigned lo0 = cvtpk(st[kf][a + 0] * inv, st[kf][a + 1] * inv);
    unsigned lo1 = cvtpk(st[kf][a + 2] * inv, st[kf][a + 3] * inv);
    unsigned hi0 = cvtpk(st[kf][a + 4] * inv, st[kf][a + 5] * inv);
    unsigned hi1 = cvtpk(st[kf][a + 6] * inv, st[kf][a + 7] * inv);
    asm volatile("v_permlane32_swap_b32 %0, %1" : "+v"(lo0), "+v"(hi0));
    asm volatile("v_permlane32_swap_b32 %0, %1" : "+v"(lo1), "+v"(hi1));
    short8 pa;
    ((unsigned*)&pa)[0] = lo0; ((unsigned*)&pa)[1] = lo1;
    ((unsigned*)&pa)[2] = hi0; ((unsigned*)&pa)[3] = hi1;
#pragma unroll
    for (int df = 0; df < 2; ++df) {
      short8 vf = *(const short8*)&vt[df * 32 + c][s * 16 + hl * 8];
      ov[df] = MFMA32_BF16(pa, vf, ov[df]);
    }
  }

  // ---- store O (already normalized): C layout col=d, row=q
  unsigned short* ob = out + (size_t)(p * 128 + wv * 32) * 1024 + h * 64;
#pragma unroll
  for (int df = 0; df < 2; ++df)
#pragma unroll
    for (int r = 0; r < 16; ++r) {
      int q = (r & 3) + 8 * (r >> 2) + 4 * hl;
      ob[(size_t)q * 1024 + df * 32 + c] = f2b(ov[df][r]);
    }
}

// ---------------- launcher ----------------

extern "C" void kernel_launch(void* const* d_in, const int* in_sizes, int n_in,
                              void* d_out, int out_size, void* d_ws, size_t ws_size,
                              hipStream_t stream) {
  const float* x  = (const float*)d_in[0];
  // d_in[1] = coords, unused by reference
  const float* Wq = (const float*)d_in[2];
  const float* bq = (const float*)d_in[3];
  const float* Wk = (const float*)d_in[4];
  const float* bk = (const float*)d_in[5];
  const float* Wv = (const float*)d_in[6];
  const float* bv = (const float*)d_in[7];
  const float* Wo = (const float*)d_in[8];
  const float* bo = (const float*)d_in[9];

  char* ws = (char*)d_ws;
  unsigned short* xb   = (unsigned short*)(ws);
  unsigned short* wqkv = (unsigned short*)(ws + 67108864);
  unsigned short* wot  = (unsigned short*)(ws + 73400320);
  float*          bqkv = (float*)(ws + 75497472);
  unsigned short* qkv  = (unsigned short*)(ws + 75509760);

  cvt_x_k<<<2048, 256, 0, stream>>>(x, xb, (32768 * 1024) / 4);
  twk4<<<1024, 256, 0, stream>>>(Wq, Wk, Wv, Wo, wqkv, wot);
  fuse_bias_k<<<12, 256, 0, stream>>>(bq, bk, bv, bqkv);

  // QKV: [32768,1024] x [3072,1024]^T -> bf16 [32768,3072]
  gemm256<false><<<1536, 512, 0, stream>>>(xb, wqkv, bqkv, qkv, 32768, 3072, 1024);
  // attention: 256 patches x 16 heads; writes bf16 [32768,1024] into xb
  attn_k<<<4096, 256, 0, stream>>>(qkv, xb);
  // O-proj: [32768,1024] x [1024,1024]^T + bo -> fp32 d_out
  gemm256<true><<<512, 512, 0, stream>>>(xb, wot, bo, d_out, 32768, 1024, 1024);
}